// Round 3
// baseline (292.022 us; speedup 1.0000x reference)
//
#include <hip/hip_runtime.h>
#include <hip/hip_bf16.h>
#include <cstdint>
#include <cstddef>

// Problem: B=64, L=2048, E=1024, A=512
#define BB   64
#define LL   2048
#define ED   1024
#define AD   512
#define BM   128          // l-rows per block
#define BK   32           // K per step
#define NCH  (LL / BM)    // 16 chunks per batch row
#define KST  (ED / BK)    // 32 K-steps

typedef short  short8  __attribute__((ext_vector_type(8)));
typedef float  f32x4   __attribute__((ext_vector_type(4)));

__device__ __forceinline__ unsigned short f2bf(float x) {
  // round-to-nearest-even fp32 -> bf16
  unsigned u = __float_as_uint(x);
  u += 0x7FFFu + ((u >> 16) & 1u);
  return (unsigned short)(u >> 16);
}

// async global->LDS DMA, 16 bytes per thread (wave-uniform LDS base + lane*16)
#define GLOAD_LDS16(gp, lp)                                                        \
  __builtin_amdgcn_global_load_lds(                                                \
      (const __attribute__((address_space(1))) unsigned int*)(gp),                 \
      (__attribute__((address_space(3))) unsigned int*)(lp), 16, 0, 0)

// ---------------- kernel 0: prep ----------------
// blocks 0..63   : dec_proj row b = dec[b] @ W_dec + b_dec  (coalesced over cols)
// blocks 64..191 : pack W_enc fp32 -> bf16 into the EXACT LDS image order used by
//   fused_kernel, so global_load_lds stays linear while LDS frag reads are
//   conflict-free (permutation lives on the global side — rule #21).
//   o = ks*16384 + i*4096 + w*512 + l*8 + j  maps to
//   k = ks*32 + (l>>4)*8 + j ; col = (i*8+w)*16 + (l&15)
__global__ __launch_bounds__(512) void prep_kernel(
    const float* __restrict__ W_enc, const float* __restrict__ dec,
    const float* __restrict__ W_dec, const float* __restrict__ b_dec,
    unsigned short* __restrict__ Wb, float* __restrict__ dp) {
  const int blk = blockIdx.x, t = threadIdx.x;
  if (blk < BB) {
    const float* drow = dec + blk * ED;
    float a0 = 0.f, a1 = 0.f, a2 = 0.f, a3 = 0.f;
    for (int k = 0; k < ED; k += 4) {
      a0 = fmaf(drow[k],     W_dec[(k)     * AD + t], a0);
      a1 = fmaf(drow[k + 1], W_dec[(k + 1) * AD + t], a1);
      a2 = fmaf(drow[k + 2], W_dec[(k + 2) * AD + t], a2);
      a3 = fmaf(drow[k + 3], W_dec[(k + 3) * AD + t], a3);
    }
    dp[blk * AD + t] = (a0 + a1) + (a2 + a3) + b_dec[t];
  } else {
    const int base = (blk - BB) * 4096;
#pragma unroll
    for (int ii = 0; ii < 8; ii++) {
      const int o  = base + ii * 512 + t;
      const int ks = o >> 14;
      const int i  = (o >> 12) & 3;
      const int w  = (o >> 9) & 7;
      const int l  = (o >> 3) & 63;
      const int j  = o & 7;
      const int k  = ks * 32 + ((l >> 4) << 3) + j;
      const int c  = ((i * 8 + w) << 4) + (l & 15);
      Wb[o] = f2bf(W_enc[k * AD + c]);
    }
  }
}

// ---------------- kernel 1: fused GEMM + tanh-score + online-softmax partials ----
// grid (NCH, BB), 512 threads = 8 waves as 2M x 4N, wave tile 64 rows x 128 cols.
// LDS layouts: 16-row/col subtiled [blk16][kg][16][8] so every frag read is a
// wave-contiguous 1 KB ds_read_b128 (zero bank conflicts).
// Pipeline: B double-buffered via global_load_lds; A reg-staged one iter deep.
// Per iter: issue B(t+1) DMAs, cvt+ds_write A(t+1), issue A(t+2) loads, MFMA,
// then s_waitcnt vmcnt(2) lgkmcnt(0) (A loads stay in flight) + raw s_barrier.
__global__ __launch_bounds__(512, 2) void fused_kernel(
    const float* __restrict__ sem, const unsigned short* __restrict__ Wb,
    const float* __restrict__ dp, const float* __restrict__ b_enc,
    const float* __restrict__ Wf,
    float* __restrict__ raw_scores,
    float* __restrict__ ws_ms, float* __restrict__ ws_o) {

  __shared__ unsigned short Alds[2][4096];    // [buf][rblk(8)][kg(4)][16][8]  16 KB
  __shared__ unsigned short Blds[2][16384];   // [buf][cblk(32)][kg(4)][16][8] 64 KB

  const int t    = threadIdx.x;
  const int lane = t & 63;
  const int wave = t >> 6;
  const int wm   = wave >> 2;   // 0..1 row half
  const int wn   = wave & 3;    // 0..3 col quarter
  const int b    = blockIdx.y;
  const int chunk= blockIdx.x;
  const int l0   = chunk * BM;

  // staging mapping
  const int srow = t >> 2;      // 0..127
  const int skg  = t & 3;       // 0..3
  const float* aptr = sem + ((size_t)(b * LL + l0 + srow)) * ED + skg * 8;
  const unsigned short* bsrc = Wb + t * 8;    // + ks*16384 + i*4096
  // A LDS write offset (shorts): subtiled layout
  const int awr = (srow >> 4) * 512 + skg * 128 + (srow & 15) * 8;

  // frag read bases (shorts): wave-contiguous, lane stride 8 shorts = 16 B
  const int arow = lane & 15;
  const int akg  = lane >> 4;
  const int afr  = wm * 4 * 512 + lane * 8;   // + mf*512
  const int bfr  = wn * 8 * 512 + lane * 8;   // + nf*512

  f32x4 acc[4][8];
#pragma unroll
  for (int i = 0; i < 4; i++)
#pragma unroll
    for (int j = 0; j < 8; j++) acc[i][j] = (f32x4)0.f;

  // ---- prologue: B(0) DMAs, A(0) regs -> cvt -> LDS0, A(1) regs in flight ----
#pragma unroll
  for (int i = 0; i < 4; i++)
    GLOAD_LDS16(bsrc + i * 4096, &Blds[0][i * 4096 + t * 8]);
  f32x4 pA0 = *(const f32x4*)(aptr);
  f32x4 pA1 = *(const f32x4*)(aptr + 4);
  f32x4 qA0 = *(const f32x4*)(aptr + BK);
  f32x4 qA1 = *(const f32x4*)(aptr + BK + 4);
  {
    short8 aw;
    aw[0]=(short)f2bf(pA0[0]); aw[1]=(short)f2bf(pA0[1]); aw[2]=(short)f2bf(pA0[2]); aw[3]=(short)f2bf(pA0[3]);
    aw[4]=(short)f2bf(pA1[0]); aw[5]=(short)f2bf(pA1[1]); aw[6]=(short)f2bf(pA1[2]); aw[7]=(short)f2bf(pA1[3]);
    *(short8*)&Alds[0][awr] = aw;
  }
  asm volatile("s_waitcnt vmcnt(2) lgkmcnt(0)" ::: "memory");  // B(0)+A(0) done; A(1) in flight
  __builtin_amdgcn_sched_barrier(0);
  __builtin_amdgcn_s_barrier();

  // ---- main loop: entering ITER(ks), regs C hold A(ks+1); loads go into L=A(ks+2)
#define ITER(ks, CA0, CA1, LA0, LA1)                                              \
  {                                                                               \
    const int cb = (ks) & 1, nb = ((ks) + 1) & 1;                                 \
    if ((ks) + 1 < KST) {  /* oldest in-flight: B(t+1) DMAs */                    \
      const unsigned short* bs = bsrc + ((ks) + 1) * 16384;                       \
      _Pragma("unroll")                                                           \
      for (int i = 0; i < 4; i++)                                                 \
        GLOAD_LDS16(bs + i * 4096, &Blds[nb][i * 4096 + t * 8]);                  \
    }                                                                             \
    __builtin_amdgcn_sched_barrier(0);  /* pin: B DMAs issue before A loads */    \
    if ((ks) + 1 < KST) {                                                         \
      short8 aw;                                                                  \
      aw[0]=(short)f2bf(CA0[0]); aw[1]=(short)f2bf(CA0[1]);                       \
      aw[2]=(short)f2bf(CA0[2]); aw[3]=(short)f2bf(CA0[3]);                       \
      aw[4]=(short)f2bf(CA1[0]); aw[5]=(short)f2bf(CA1[1]);                       \
      aw[6]=(short)f2bf(CA1[2]); aw[7]=(short)f2bf(CA1[3]);                       \
      *(short8*)&Alds[nb][awr] = aw;                                              \
    }                                                                             \
    if ((ks) + 2 < KST) {                                                         \
      const float* ap = aptr + ((ks) + 2) * BK;                                   \
      LA0 = *(const f32x4*)(ap);                                                  \
      LA1 = *(const f32x4*)(ap + 4);                                              \
    }                                                                             \
    short8 av[4], bv[8];                                                          \
    _Pragma("unroll")                                                             \
    for (int mf = 0; mf < 4; mf++)                                                \
      av[mf] = *(const short8*)&Alds[cb][afr + mf * 512];                         \
    _Pragma("unroll")                                                             \
    for (int nf = 0; nf < 8; nf++)                                                \
      bv[nf] = *(const short8*)&Blds[cb][bfr + nf * 512];                         \
    __builtin_amdgcn_s_setprio(1);                                                \
    _Pragma("unroll")                                                             \
    for (int mf = 0; mf < 4; mf++)                                                \
      _Pragma("unroll")                                                           \
      for (int nf = 0; nf < 8; nf++)                                              \
        acc[mf][nf] = __builtin_amdgcn_mfma_f32_16x16x32_bf16(av[mf], bv[nf], acc[mf][nf], 0, 0, 0); \
    __builtin_amdgcn_s_setprio(0);                                                \
    if ((ks) + 2 < KST) {  /* leave the 2 A(t+2) loads in flight */               \
      asm volatile("s_waitcnt vmcnt(2) lgkmcnt(0)" ::: "memory");                 \
    } else {                                                                      \
      asm volatile("s_waitcnt vmcnt(0) lgkmcnt(0)" ::: "memory");                 \
    }                                                                             \
    __builtin_amdgcn_sched_barrier(0);                                            \
    __builtin_amdgcn_s_barrier();                                                 \
  }

  for (int kk = 0; kk < KST; kk += 2) {
    ITER(kk,     qA0, qA1, pA0, pA1);
    ITER(kk + 1, pA0, pA1, qA0, qA1);
  }
#undef ITER

  // ---- epilogue smem carved out of Blds (all B reads done past final barrier) --
  float* eb = (float*)&Blds[0][0];
  float (*sc_part)[4]   = (float (*)[4])eb;            // 128*4
  float* scores_lds     = eb + 512;                    // 128
  float* weight         = eb + 640;                    // 128
  float (*o_lds)[AD]    = (float (*)[AD])(eb + 768);   // 2*512
  float* bcv            = eb + 1792;                   // 2

  // ---- add b_enc, tanh-score, online-softmax partials ----
  float dpv[8], wfv[8], bev[8];
#pragma unroll
  for (int nf = 0; nf < 8; nf++) {
    const int c = wn * 128 + nf * 16 + arow;
    dpv[nf] = dp[b * AD + c];
    wfv[nf] = Wf[c];
    bev[nf] = b_enc[c];
  }
#pragma unroll
  for (int mf = 0; mf < 4; mf++) {
#pragma unroll
    for (int r = 0; r < 4; r++) {
      float p = 0.f;
#pragma unroll
      for (int nf = 0; nf < 8; nf++) {
        float e = acc[mf][nf][r] + bev[nf];
        acc[mf][nf][r] = e;                      // keep enc_proj (+b_enc) for o-accum
        float x = e + dpv[nf];
        float ex = __expf(2.f * x);              // tanh via exp
        float th = 1.f - 2.f / (ex + 1.f);
        p = fmaf(th, wfv[nf], p);
      }
      p += __shfl_xor(p, 1); p += __shfl_xor(p, 2);
      p += __shfl_xor(p, 4); p += __shfl_xor(p, 8);
      if (arow == 0) sc_part[wm * 64 + mf * 16 + akg * 4 + r][wn] = p;
    }
  }
  __syncthreads();

  if (t < BM) {
    float s = sc_part[t][0] + sc_part[t][1] + sc_part[t][2] + sc_part[t][3];
    scores_lds[t] = s;
    raw_scores[(size_t)b * LL + l0 + t] = s;     // raw; finalize normalizes in place
  }
  __syncthreads();
  if (t < 64) {
    float m = fmaxf(scores_lds[t], scores_lds[t + 64]);
#pragma unroll
    for (int off = 1; off < 64; off <<= 1) m = fmaxf(m, __shfl_xor(m, off));
    if (t == 0) bcv[0] = m;
  }
  __syncthreads();
  const float m_c = bcv[0];
  if (t < BM) weight[t] = __expf(scores_lds[t] - m_c);
  __syncthreads();
  if (t < 64) {
    float s = weight[t] + weight[t + 64];
#pragma unroll
    for (int off = 1; off < 64; off <<= 1) s += __shfl_xor(s, off);
    if (t == 0) bcv[1] = s;
  }

  float wv[4][4];
#pragma unroll
  for (int mf = 0; mf < 4; mf++)
#pragma unroll
    for (int r = 0; r < 4; r++) wv[mf][r] = weight[wm * 64 + mf * 16 + akg * 4 + r];
#pragma unroll
  for (int nf = 0; nf < 8; nf++) {
    float cp = 0.f;
#pragma unroll
    for (int mf = 0; mf < 4; mf++)
#pragma unroll
      for (int r = 0; r < 4; r++) cp = fmaf(wv[mf][r], acc[mf][nf][r], cp);
    cp += __shfl_xor(cp, 16);
    cp += __shfl_xor(cp, 32);
    if (lane < 16) o_lds[wm][wn * 128 + nf * 16 + lane] = cp;
  }
  __syncthreads();
  if (t < AD)
    ws_o[((size_t)b * NCH + chunk) * AD + t] = o_lds[0][t] + o_lds[1][t];
  if (t == 0) {
    ws_ms[(b * NCH + chunk) * 2]     = m_c;
    ws_ms[(b * NCH + chunk) * 2 + 1] = bcv[1];
  }
}

// ---------------- kernel 2: finalize (merge chunk partials, normalize) ----------
__global__ __launch_bounds__(256) void finalize_kernel(
    const float* __restrict__ ws_ms, const float* __restrict__ ws_o,
    float* __restrict__ out0, float* __restrict__ outS) {
  const int b = blockIdx.x, t = threadIdx.x;
  float ms[NCH], ss[NCH];
  float M = -1e30f;
#pragma unroll
  for (int i = 0; i < NCH; i++) {
    ms[i] = ws_ms[(b * NCH + i) * 2];
    ss[i] = ws_ms[(b * NCH + i) * 2 + 1];
    M = fmaxf(M, ms[i]);
  }
  float S = 0.f, w[NCH];
#pragma unroll
  for (int i = 0; i < NCH; i++) { w[i] = __expf(ms[i] - M); S = fmaf(ss[i], w[i], S); }
  const float invS = 1.f / S;
  for (int c = t; c < AD; c += 256) {
    float a = 0.f;
#pragma unroll
    for (int i = 0; i < NCH; i++) a = fmaf(ws_o[((size_t)b * NCH + i) * AD + c], w[i], a);
    out0[b * AD + c] = a * invS;
  }
  for (int l = t; l < LL; l += 256) {
    float r = outS[(size_t)b * LL + l];
    outS[(size_t)b * LL + l] = __expf(r - M) * invS;
  }
}

extern "C" void kernel_launch(void* const* d_in, const int* in_sizes, int n_in,
                              void* d_out, int out_size, void* d_ws, size_t ws_size,
                              hipStream_t stream) {
  const float* sem    = (const float*)d_in[0];
  const float* dec    = (const float*)d_in[1];
  const float* W_enc  = (const float*)d_in[2];
  const float* b_enc  = (const float*)d_in[3];
  const float* W_dec  = (const float*)d_in[4];
  const float* b_dec  = (const float*)d_in[5];
  const float* W_full = (const float*)d_in[6];
  // d_in[7] = b_full: constant shift, cancels in softmax.

  float* out0 = (float*)d_out;            // att_output [64][512]
  float* outS = out0 + BB * AD;           // att_scores [64][2048]

  char* ws = (char*)d_ws;
  unsigned short* Wb = (unsigned short*)ws;                          // 1 MB bf16 packed W_enc (LDS image order)
  float* dpw   = (float*)(ws + (1 << 20));                           // 128 KB dec_proj+b_dec
  float* ws_ms = (float*)(ws + (1 << 20) + (128 << 10));             // 8 KB (m,s) per chunk
  float* ws_o  = (float*)(ws + (1 << 20) + (128 << 10) + (8 << 10)); // 2 MB o partials

  prep_kernel<<<BB + 128, 512, 0, stream>>>(W_enc, dec, W_dec, b_dec, Wb, dpw);
  dim3 g1(NCH, BB);
  fused_kernel<<<g1, 512, 0, stream>>>(sem, Wb, dpw, b_enc, W_full, outS, ws_ms, ws_o);
  finalize_kernel<<<BB, 256, 0, stream>>>(ws_ms, ws_o, out0, outS);
}

// Round 4
// 283.558 us; speedup vs baseline: 1.0299x; 1.0299x over previous
//
#include <hip/hip_runtime.h>
#include <hip/hip_bf16.h>
#include <cstdint>
#include <cstddef>

// Problem: B=64, L=2048, E=1024, A=512
#define BB   64
#define LL   2048
#define ED   1024
#define AD   512
#define BM   64           // l-rows per block (2 blocks/CU co-resident)
#define BK   32           // K per step
#define NCH  (LL / BM)    // 32 chunks per batch row
#define KST  (ED / BK)    // 32 K-steps

typedef short  short8  __attribute__((ext_vector_type(8)));
typedef float  f32x4   __attribute__((ext_vector_type(4)));

__device__ __forceinline__ unsigned short f2bf(float x) {
  // round-to-nearest-even fp32 -> bf16
  unsigned u = __float_as_uint(x);
  u += 0x7FFFu + ((u >> 16) & 1u);
  return (unsigned short)(u >> 16);
}

// async global->LDS DMA, 16 bytes per thread (wave-uniform LDS base + lane*16)
#define GLOAD_LDS16(gp, lp)                                                        \
  __builtin_amdgcn_global_load_lds(                                                \
      (const __attribute__((address_space(1))) unsigned int*)(gp),                 \
      (__attribute__((address_space(3))) unsigned int*)(lp), 16, 0, 0)

// ---------------- kernel 0: prep ----------------
// blocks 0..63   : dec_proj row b = dec[b] @ W_dec + b_dec  (coalesced over cols)
// blocks 64..191 : pack W_enc fp32 -> bf16 into the EXACT LDS image order used by
//   fused_kernel (linear o). Decode (within a 16 KB ks-tile):
//   cblk=(o>>9)&31, kg=(o>>7)&3, r=(o>>3)&15, j=o&7 ->
//   k = ks*32 + kg*8 + j ; col = cblk*16 + r
__global__ __launch_bounds__(512) void prep_kernel(
    const float* __restrict__ W_enc, const float* __restrict__ dec,
    const float* __restrict__ W_dec, const float* __restrict__ b_dec,
    unsigned short* __restrict__ Wb, float* __restrict__ dp) {
  const int blk = blockIdx.x, t = threadIdx.x;
  if (blk < BB) {
    const float* drow = dec + blk * ED;
    float a0 = 0.f, a1 = 0.f, a2 = 0.f, a3 = 0.f;
    for (int k = 0; k < ED; k += 4) {
      a0 = fmaf(drow[k],     W_dec[(k)     * AD + t], a0);
      a1 = fmaf(drow[k + 1], W_dec[(k + 1) * AD + t], a1);
      a2 = fmaf(drow[k + 2], W_dec[(k + 2) * AD + t], a2);
      a3 = fmaf(drow[k + 3], W_dec[(k + 3) * AD + t], a3);
    }
    dp[blk * AD + t] = (a0 + a1) + (a2 + a3) + b_dec[t];
  } else {
    const int base = (blk - BB) * 4096;
#pragma unroll
    for (int ii = 0; ii < 8; ii++) {
      const int o    = base + ii * 512 + t;
      const int ks   = o >> 14;
      const int cblk = (o >> 9) & 31;
      const int kg   = (o >> 7) & 3;
      const int r    = (o >> 3) & 15;
      const int j    = o & 7;
      const int k    = ks * 32 + kg * 8 + j;
      const int c    = cblk * 16 + r;
      Wb[o] = f2bf(W_enc[k * AD + c]);
    }
  }
}

// ---------------- kernel 1: fused GEMM + tanh-score + online-softmax partials ----
// grid (NCH, BB), 256 threads = 4 waves (1M x 4N), wave tile 64 rows x 128 cols.
// 2 blocks co-resident per CU (72 KB LDS, ~232 regs/thread) -> phases interleave.
// B double-buffered via global_load_lds (8 DMAs/thread/step); A reg-staged 2 steps
// deep. End-of-step: s_waitcnt vmcnt(2) (A loads stay in flight) + raw s_barrier.
__global__ __launch_bounds__(256, 2) void fused_kernel(
    const float* __restrict__ sem, const unsigned short* __restrict__ Wb,
    const float* __restrict__ dp, const float* __restrict__ b_enc,
    const float* __restrict__ Wf,
    float* __restrict__ raw_scores,
    float* __restrict__ ws_ms, float* __restrict__ ws_o) {

  __shared__ unsigned short Alds[2][2048];    // [buf][rblk(4)][kg(4)][16][8]   8 KB
  __shared__ unsigned short Blds[2][16384];   // [buf][cblk(32)][kg(4)][16][8] 64 KB

  const int t    = threadIdx.x;
  const int lane = t & 63;
  const int wn   = t >> 6;      // 0..3 col quarter (4 waves)
  const int b    = blockIdx.y;
  const int chunk= blockIdx.x;
  const int l0   = chunk * BM;

  // staging mapping
  const int srow = t >> 2;      // 0..63
  const int skg  = t & 3;       // 0..3
  const float* aptr = sem + ((size_t)(b * LL + l0 + srow)) * ED + skg * 8;
  const unsigned short* bsrc = Wb + t * 8;    // + ks*16384 + i*2048
  const int awr = (srow >> 4) * 512 + skg * 128 + (srow & 15) * 8;

  // frag read bases (shorts): wave-contiguous, lane stride 8 shorts = 16 B
  const int arow = lane & 15;
  const int akg  = lane >> 4;
  const int afr  = lane * 8;                  // + mf*512
  const int bfr  = wn * 8 * 512 + lane * 8;   // + nf*512

  f32x4 acc[4][8];
#pragma unroll
  for (int i = 0; i < 4; i++)
#pragma unroll
    for (int j = 0; j < 8; j++) acc[i][j] = (f32x4)0.f;

  // ---- prologue: B(0) DMAs, A(0) regs -> cvt -> LDS0, A(1) regs in flight ----
#pragma unroll
  for (int i = 0; i < 8; i++)
    GLOAD_LDS16(bsrc + i * 2048, &Blds[0][i * 2048 + t * 8]);
  f32x4 pA0 = *(const f32x4*)(aptr);
  f32x4 pA1 = *(const f32x4*)(aptr + 4);
  f32x4 qA0 = *(const f32x4*)(aptr + BK);
  f32x4 qA1 = *(const f32x4*)(aptr + BK + 4);
  {
    short8 aw;
    aw[0]=(short)f2bf(pA0[0]); aw[1]=(short)f2bf(pA0[1]); aw[2]=(short)f2bf(pA0[2]); aw[3]=(short)f2bf(pA0[3]);
    aw[4]=(short)f2bf(pA1[0]); aw[5]=(short)f2bf(pA1[1]); aw[6]=(short)f2bf(pA1[2]); aw[7]=(short)f2bf(pA1[3]);
    *(short8*)&Alds[0][awr] = aw;
  }
  asm volatile("s_waitcnt vmcnt(2) lgkmcnt(0)" ::: "memory");  // B(0)+A(0) done; A(1) in flight
  __builtin_amdgcn_sched_barrier(0);
  __builtin_amdgcn_s_barrier();

  // ---- main loop: entering ITER(ks), regs C hold A(ks+1); loads go into L=A(ks+2)
#define ITER(ks, CA0, CA1, LA0, LA1)                                              \
  {                                                                               \
    const int cb = (ks) & 1, nb = ((ks) + 1) & 1;                                 \
    if ((ks) + 1 < KST) {  /* oldest in-flight: B(t+1) DMAs */                    \
      const unsigned short* bs = bsrc + ((ks) + 1) * 16384;                       \
      _Pragma("unroll")                                                           \
      for (int i = 0; i < 8; i++)                                                 \
        GLOAD_LDS16(bs + i * 2048, &Blds[nb][i * 2048 + t * 8]);                  \
    }                                                                             \
    __builtin_amdgcn_sched_barrier(0);  /* pin: B DMAs issue before A cvt/loads */\
    if ((ks) + 1 < KST) {                                                         \
      short8 aw;                                                                  \
      aw[0]=(short)f2bf(CA0[0]); aw[1]=(short)f2bf(CA0[1]);                       \
      aw[2]=(short)f2bf(CA0[2]); aw[3]=(short)f2bf(CA0[3]);                       \
      aw[4]=(short)f2bf(CA1[0]); aw[5]=(short)f2bf(CA1[1]);                       \
      aw[6]=(short)f2bf(CA1[2]); aw[7]=(short)f2bf(CA1[3]);                       \
      *(short8*)&Alds[nb][awr] = aw;                                              \
    }                                                                             \
    if ((ks) + 2 < KST) {                                                         \
      const float* ap = aptr + ((ks) + 2) * BK;                                   \
      LA0 = *(const f32x4*)(ap);                                                  \
      LA1 = *(const f32x4*)(ap + 4);                                              \
    }                                                                             \
    short8 av[4], bv[8];                                                          \
    _Pragma("unroll")                                                             \
    for (int mf = 0; mf < 4; mf++)                                                \
      av[mf] = *(const short8*)&Alds[cb][afr + mf * 512];                         \
    _Pragma("unroll")                                                             \
    for (int nf = 0; nf < 8; nf++)                                                \
      bv[nf] = *(const short8*)&Blds[cb][bfr + nf * 512];                         \
    __builtin_amdgcn_s_setprio(1);                                                \
    _Pragma("unroll")                                                             \
    for (int mf = 0; mf < 4; mf++)                                                \
      _Pragma("unroll")                                                           \
      for (int nf = 0; nf < 8; nf++)                                              \
        acc[mf][nf] = __builtin_amdgcn_mfma_f32_16x16x32_bf16(av[mf], bv[nf], acc[mf][nf], 0, 0, 0); \
    __builtin_amdgcn_s_setprio(0);                                                \
    if ((ks) + 2 < KST) {  /* leave the 2 A(t+2) loads in flight */               \
      asm volatile("s_waitcnt vmcnt(2) lgkmcnt(0)" ::: "memory");                 \
    } else {                                                                      \
      asm volatile("s_waitcnt vmcnt(0) lgkmcnt(0)" ::: "memory");                 \
    }                                                                             \
    __builtin_amdgcn_sched_barrier(0);                                            \
    __builtin_amdgcn_s_barrier();                                                 \
  }

  for (int kk = 0; kk < KST; kk += 2) {
    ITER(kk,     qA0, qA1, pA0, pA1);
    ITER(kk + 1, pA0, pA1, qA0, qA1);
  }
#undef ITER

  // ---- epilogue smem carved out of Blds (all B reads done past final barrier) --
  float* eb = (float*)&Blds[0][0];
  float (*sc_part)[4] = (float (*)[4])eb;     // 64*4
  float* weight       = eb + 256;             // 64
  float* scores_lds   = eb + 320;             // 64

  // ---- add b_enc, tanh-score ----
  float dpv[8], wfv[8], bev[8];
#pragma unroll
  for (int nf = 0; nf < 8; nf++) {
    const int c = wn * 128 + nf * 16 + arow;
    dpv[nf] = dp[b * AD + c];
    wfv[nf] = Wf[c];
    bev[nf] = b_enc[c];
  }
#pragma unroll
  for (int mf = 0; mf < 4; mf++) {
#pragma unroll
    for (int r = 0; r < 4; r++) {
      float p = 0.f;
#pragma unroll
      for (int nf = 0; nf < 8; nf++) {
        float e = acc[mf][nf][r] + bev[nf];
        acc[mf][nf][r] = e;                      // keep enc_proj (+b_enc) for o-accum
        float x = e + dpv[nf];
        float ex = __expf(2.f * x);              // tanh via exp
        float th = 1.f - 2.f / (ex + 1.f);
        p = fmaf(th, wfv[nf], p);
      }
      p += __shfl_xor(p, 1); p += __shfl_xor(p, 2);
      p += __shfl_xor(p, 4); p += __shfl_xor(p, 8);
      if (arow == 0) sc_part[mf * 16 + akg * 4 + r][wn] = p;
    }
  }
  __syncthreads();

  // ---- chunk softmax stats: all 64 rows live in wave 0 ----
  if (t < BM) {
    float s = sc_part[t][0] + sc_part[t][1] + sc_part[t][2] + sc_part[t][3];
    raw_scores[(size_t)b * LL + l0 + t] = s;     // raw; finalize normalizes in place
    float m = s;
#pragma unroll
    for (int off = 1; off < 64; off <<= 1) m = fmaxf(m, __shfl_xor(m, off));
    float w = __expf(s - m);
    weight[t] = w;
    float ss = w;
#pragma unroll
    for (int off = 1; off < 64; off <<= 1) ss += __shfl_xor(ss, off);
    if (t == 0) {
      ws_ms[(b * NCH + chunk) * 2]     = m;
      ws_ms[(b * NCH + chunk) * 2 + 1] = ss;
    }
  }
  __syncthreads();

  // ---- o partial: weighted sum over the 64 rows of enc_proj ----
  float wv[4][4];
#pragma unroll
  for (int mf = 0; mf < 4; mf++)
#pragma unroll
    for (int r = 0; r < 4; r++) wv[mf][r] = weight[mf * 16 + akg * 4 + r];
#pragma unroll
  for (int nf = 0; nf < 8; nf++) {
    float cp = 0.f;
#pragma unroll
    for (int mf = 0; mf < 4; mf++)
#pragma unroll
      for (int r = 0; r < 4; r++) cp = fmaf(wv[mf][r], acc[mf][nf][r], cp);
    cp += __shfl_xor(cp, 16);
    cp += __shfl_xor(cp, 32);
    if (lane < 16)
      ws_o[((size_t)b * NCH + chunk) * AD + wn * 128 + nf * 16 + lane] = cp;
  }
}

// ---------------- kernel 2: finalize (merge chunk partials, normalize) ----------
__global__ __launch_bounds__(256) void finalize_kernel(
    const float* __restrict__ ws_ms, const float* __restrict__ ws_o,
    float* __restrict__ out0, float* __restrict__ outS) {
  const int b = blockIdx.x, t = threadIdx.x;
  float ms[NCH], ss[NCH];
  float M = -1e30f;
#pragma unroll
  for (int i = 0; i < NCH; i++) {
    ms[i] = ws_ms[(b * NCH + i) * 2];
    ss[i] = ws_ms[(b * NCH + i) * 2 + 1];
    M = fmaxf(M, ms[i]);
  }
  float S = 0.f, w[NCH];
#pragma unroll
  for (int i = 0; i < NCH; i++) { w[i] = __expf(ms[i] - M); S = fmaf(ss[i], w[i], S); }
  const float invS = 1.f / S;
  for (int c = t; c < AD; c += 256) {
    float a = 0.f;
#pragma unroll
    for (int i = 0; i < NCH; i++) a = fmaf(ws_o[((size_t)b * NCH + i) * AD + c], w[i], a);
    out0[b * AD + c] = a * invS;
  }
  for (int l = t; l < LL; l += 256) {
    float r = outS[(size_t)b * LL + l];
    outS[(size_t)b * LL + l] = __expf(r - M) * invS;
  }
}

extern "C" void kernel_launch(void* const* d_in, const int* in_sizes, int n_in,
                              void* d_out, int out_size, void* d_ws, size_t ws_size,
                              hipStream_t stream) {
  const float* sem    = (const float*)d_in[0];
  const float* dec    = (const float*)d_in[1];
  const float* W_enc  = (const float*)d_in[2];
  const float* b_enc  = (const float*)d_in[3];
  const float* W_dec  = (const float*)d_in[4];
  const float* b_dec  = (const float*)d_in[5];
  const float* W_full = (const float*)d_in[6];
  // d_in[7] = b_full: constant shift, cancels in softmax.

  float* out0 = (float*)d_out;            // att_output [64][512]
  float* outS = out0 + BB * AD;           // att_scores [64][2048]

  char* ws = (char*)d_ws;
  unsigned short* Wb = (unsigned short*)ws;                          // 1 MB bf16 packed W_enc (LDS image order)
  float* dpw   = (float*)(ws + (1 << 20));                           // 128 KB dec_proj+b_dec
  float* ws_ms = (float*)(ws + (1 << 20) + (128 << 10));             // 16 KB (m,s) per chunk
  float* ws_o  = (float*)(ws + (1 << 20) + (144 << 10));             // 4 MB o partials

  prep_kernel<<<BB + 128, 512, 0, stream>>>(W_enc, dec, W_dec, b_dec, Wb, dpw);
  dim3 g1(NCH, BB);
  fused_kernel<<<g1, 256, 0, stream>>>(sem, Wb, dpw, b_enc, W_full, outS, ws_ms, ws_o);
  finalize_kernel<<<BB, 256, 0, stream>>>(ws_ms, ws_o, out0, outS);
}